// Round 8
// baseline (221.892 us; speedup 1.0000x reference)
//
#include <hip/hip_runtime.h>
#include <hip/hip_bf16.h>
#include <math.h>

// Problem constants
#define BATCH 2
#define SEQ 2048
#define NFEAT 1024
#define NHEAD 16
#define DHEAD 64
#define MROWS (BATCH * SEQ)      // 4096
#define NQKV (3 * NHEAD * DHEAD) // 3072

typedef __attribute__((ext_vector_type(8))) short short8;
typedef __attribute__((ext_vector_type(4))) float floatx4;
typedef __attribute__((ext_vector_type(16))) float floatx16;
typedef __attribute__((ext_vector_type(4))) unsigned int uintx4;

#define CEXP 0.18033688f   // log2(e)/sqrt(64), applied in gemm_qkv Q epilogue

__device__ __forceinline__ unsigned short f2bf(float f) {
    unsigned int u = __float_as_uint(f);
    u += 0x7fff + ((u >> 16) & 1);   // round-to-nearest-even
    return (unsigned short)(u >> 16);
}

__device__ __forceinline__ float fast_exp2(float x) {
    return __builtin_amdgcn_exp2f(x);   // v_exp_f32: D = 2^S0
}

__device__ __forceinline__ uint pack_bf16x2(float lo, float hi) {
    float2 t; t.x = lo; t.y = hi;
    __hip_bfloat162 h = __float22bfloat162_rn(t);   // v_cvt_pk_bf16_f32
    union { __hip_bfloat162 h; uint u; } c; c.h = h;
    return c.u;
}

__device__ __forceinline__ void async16(const void* g, void* l) {
    __builtin_amdgcn_global_load_lds(
        (const __attribute__((address_space(1))) void*)g,
        (__attribute__((address_space(3))) void*)l, 16, 0, 0);
}

// raw barrier + counted vmcnt (T4): loads stay in flight across barriers
#define BAR_RAW() asm volatile("s_barrier" ::: "memory")
#define WAITV4()  { asm volatile("s_waitcnt vmcnt(4)" ::: "memory"); __builtin_amdgcn_sched_barrier(0); }
#define WAITV0()  { asm volatile("s_waitcnt vmcnt(0)" ::: "memory"); __builtin_amdgcn_sched_barrier(0); }

// ---------------------------------------------------------------------------
// fp32 -> bf16 convert of x, w_qkv, w_proj, merged; output chunk-swizzled in
// 32-wide k-windows (key (row>>1)&3) so GEMM LDS fragment reads are 2-way max.
// ---------------------------------------------------------------------------
__global__ void cvt_swz(const float* __restrict__ x, const float* __restrict__ wq,
                        const float* __restrict__ wp,
                        ushort* __restrict__ xb, ushort* __restrict__ wqb,
                        ushort* __restrict__ wpb) {
    const int NX = MROWS * NFEAT / 4, NWQ = NQKV * NFEAT / 4, NWP = NFEAT * NFEAT / 4;
    int i = blockIdx.x * blockDim.x + threadIdx.x;
    if (i >= NX + NWQ + NWP) return;
    const float* src; ushort* dst; int idx4;
    if (i < NX)            { src = x;  dst = xb;  idx4 = i; }
    else if (i < NX + NWQ) { src = wq; dst = wqb; idx4 = i - NX; }
    else                   { src = wp; dst = wpb; idx4 = i - NX - NWQ; }
    float4 v = ((const float4*)src)[idx4];
    ushort4 o;
    o.x = f2bf(v.x); o.y = f2bf(v.y); o.z = f2bf(v.z); o.w = f2bf(v.w);
    const int e = idx4 * 4;
    const int k = e & (NFEAT - 1);
    const int row = e >> 10;                     // all arrays have K = 1024
    const int kp = (k & ~31) | (((((k >> 3) & 3) ^ ((row >> 1) & 3))) << 3) | (k & 7);
    *(ushort4*)(dst + (size_t)row * NFEAT + kp) = o;
}

// ---------------------------------------------------------------------------
// QKV GEMM: 128x128 tile, BK=64 (16 barriers x 32 MFMAs). 1D grid 768 with
// XCD-locality decode: 8 regions of 8 m-tiles x 12 n-tiles, region = id%8,
// so blocks sharing A-rows/W-cols co-reside on one XCD's L2.
// Epilogue is the round-12 measured-good form (scalar Q/K + V^T transpose).
// NOTE (rounds 10/11): swapped-operand epilogues caused ~8x HBM write
// amplification (166/198 MB vs 24 MB ideal). Watch WRITE_SIZE on any change.
// ---------------------------------------------------------------------------
__global__ __launch_bounds__(256, 3)
void gemm_qkv(const ushort* __restrict__ A, const ushort* __restrict__ W,
              ushort* __restrict__ qb, ushort* __restrict__ kb, ushort* __restrict__ vtb) {
    __shared__ ushort smem[16384];      // As: [0,8192) Bs: [8192,16384); epilogue reuses front
    ushort* As = smem;
    ushort* Bs = smem + 8192;
    const int tid = threadIdx.x;
    const int wave = tid >> 6, lane = tid & 63;
    // XCD-locality decode: region (id&7) = 8 by x 12 bx; slot = id>>3 in [0,96)
    const int id = blockIdx.x;
    const int xcd = id & 7, slot = id >> 3;
    const int by = (xcd >> 1) * 8 + slot / 12;
    const int bx = (xcd & 1) * 12 + slot % 12;
    const int m0 = by * 128, n0 = bx * 128;
    const int wm = (wave >> 1) * 64, wn = (wave & 1) * 64;
    const int lr = lane & 15, lg = lane >> 4;
    const int kswz = (lg ^ ((lr >> 1) & 3)) * 8;   // de-swizzle slot within 32-window

    floatx4 acc[4][4] = {};

    for (int k0 = 0; k0 < NFEAT; k0 += 64) {
#pragma unroll
        for (int q = 0; q < 4; ++q) {
            const int s = q * 256 + tid;
            const int row = s >> 3, kc = (s & 7) * 8;
            async16(A + (size_t)(m0 + row) * NFEAT + k0 + kc, (void*)(As + s * 8));
            async16(W + (size_t)(n0 + row) * NFEAT + k0 + kc, (void*)(Bs + s * 8));
        }
        __syncthreads();
#pragma unroll
        for (int kk = 0; kk < 2; ++kk) {
            short8 a[4], b[4];
#pragma unroll
            for (int i = 0; i < 4; ++i)
                a[i] = *(const short8*)(As + (wm + i * 16 + lr) * 64 + kk * 32 + kswz);
#pragma unroll
            for (int j = 0; j < 4; ++j)
                b[j] = *(const short8*)(Bs + (wn + j * 16 + lr) * 64 + kk * 32 + kswz);
#pragma unroll
            for (int i = 0; i < 4; ++i)
#pragma unroll
                for (int j = 0; j < 4; ++j)
                    acc[i][j] = __builtin_amdgcn_mfma_f32_16x16x32_bf16(a[i], b[j], acc[i][j], 0, 0, 0);
        }
        __syncthreads();
    }

    const int t = n0 >> 10;         // block-uniform
    const int bidx = m0 >> 11;
    if (t < 2) {
#pragma unroll
        for (int i = 0; i < 4; ++i)
#pragma unroll
            for (int j = 0; j < 4; ++j)
#pragma unroll
                for (int r = 0; r < 4; ++r) {
                    const int m = m0 + wm + i * 16 + lg * 4 + r;
                    const int n = n0 + wn + j * 16 + lr;
                    const int s = m & (SEQ - 1);
                    const int rem = n & 1023, h = rem >> 6, d = rem & 63;
                    if (t == 0) {
                        qb[((size_t)(bidx * NHEAD + h) * SEQ + s) * DHEAD + d] =
                            f2bf(acc[i][j][r] * CEXP);
                    } else {
                        const int dcol = ((((d >> 3) ^ (s & 7)) << 3)) | (d & 7);
                        kb[((size_t)(bidx * NHEAD + h) * SEQ + s) * DHEAD + dcol] =
                            f2bf(acc[i][j][r]);
                    }
                }
    } else {
        // V^T: LDS transpose, two 64-row m-halves, coalesced 16B stores.
#pragma unroll
        for (int hhalf = 0; hhalf < 2; ++hhalf) {
            if ((wm >> 6) == hhalf) {
#pragma unroll
                for (int i = 0; i < 4; ++i) {
                    const int chunk = i * 2 + (lg >> 1);
#pragma unroll
                    for (int j = 0; j < 4; ++j) {
                        const int n = wn + j * 16 + lr;
                        uint2 pk;
                        pk.x = pack_bf16x2(acc[i][j][0], acc[i][j][1]);
                        pk.y = pack_bf16x2(acc[i][j][2], acc[i][j][3]);
                        *(uint2*)(smem + n * 64 + ((chunk ^ (n & 7)) * 8) + (lg & 1) * 4) = pk;
                    }
                }
            }
            __syncthreads();
            // s index is WITHIN-BATCH: (m0 & (SEQ-1)), not m0.
            const int s_base = (m0 & (SEQ - 1)) + hhalf * 64;
#pragma unroll
            for (int it = 0; it < 4; ++it) {
                const int n_r = (tid >> 3) + it * 32;
                const int p = tid & 7;
                short8 rowv = *(const short8*)(smem + n_r * 64 + p * 8);
                const int nglob = n0 + n_r;
                const int d = nglob & 63, hh = (nglob & 1023) >> 6;
                *(short8*)(vtb + ((size_t)(bidx * NHEAD + hh) * DHEAD + d) * SEQ + s_base + p * 8) = rowv;
            }
            __syncthreads();
        }
    }
}

// ---------------------------------------------------------------------------
// Output projection GEMM (round-2 measured-good form): 128m x 64n, BK=64.
// 1D grid 512 with XCD decode: 8 regions of 8 by x 8 bx, 2 blocks/CU.
// out = A @ w_proj^T + bias, fp32.
// ---------------------------------------------------------------------------
__global__ __launch_bounds__(256, 2)
void gemm_proj(const ushort* __restrict__ A, const ushort* __restrict__ W,
               const float* __restrict__ bias, float* __restrict__ Cout) {
    __shared__ ushort As[128 * 64];   // 16 KB
    __shared__ ushort Bs[64 * 64];    // 8 KB
    const int tid = threadIdx.x;
    const int wave = tid >> 6, lane = tid & 63;
    const int id = blockIdx.x;
    const int xcd = id & 7, slot = id >> 3;           // slot in [0,64)
    const int by = (xcd >> 1) * 8 + (slot >> 3);
    const int bx = (xcd & 1) * 8 + (slot & 7);
    const int m0 = by * 128, n0 = bx * 64;
    const int wm = (wave >> 1) * 64, wn = (wave & 1) * 32;
    const int lr = lane & 15, lg = lane >> 4;
    const int kswz = (lg ^ ((lr >> 1) & 3)) * 8;

    floatx4 acc[4][2] = {};

    for (int k0 = 0; k0 < NFEAT; k0 += 64) {
#pragma unroll
        for (int q = 0; q < 4; ++q) {
            const int s = q * 256 + tid;
            const int row = s >> 3, kc = (s & 7) * 8;
            async16(A + (size_t)(m0 + row) * NFEAT + k0 + kc, (void*)(As + s * 8));
        }
#pragma unroll
        for (int q = 0; q < 2; ++q) {
            const int s = q * 256 + tid;
            const int row = s >> 3, kc = (s & 7) * 8;
            async16(W + (size_t)(n0 + row) * NFEAT + k0 + kc, (void*)(Bs + s * 8));
        }
        __syncthreads();
#pragma unroll
        for (int kk = 0; kk < 2; ++kk) {
            short8 a[4], b[2];
#pragma unroll
            for (int i = 0; i < 4; ++i)
                a[i] = *(const short8*)(As + (wm + i * 16 + lr) * 64 + kk * 32 + kswz);
#pragma unroll
            for (int j = 0; j < 2; ++j)
                b[j] = *(const short8*)(Bs + (wn + j * 16 + lr) * 64 + kk * 32 + kswz);
#pragma unroll
            for (int i = 0; i < 4; ++i)
#pragma unroll
                for (int j = 0; j < 2; ++j)
                    acc[i][j] = __builtin_amdgcn_mfma_f32_16x16x32_bf16(a[i], b[j], acc[i][j], 0, 0, 0);
        }
        __syncthreads();
    }

#pragma unroll
    for (int i = 0; i < 4; ++i)
#pragma unroll
        for (int j = 0; j < 2; ++j)
#pragma unroll
            for (int r = 0; r < 4; ++r) {
                const int m = m0 + wm + i * 16 + lg * 4 + r;
                const int n = n0 + wn + j * 16 + lr;
                Cout[(size_t)m * NFEAT + n] = acc[i][j][r] + bias[n];
            }
}

// ---------------------------------------------------------------------------
// Flash attention v13: software-pipelined phases. v12 geometry/addressing
// byte-identical (512 thr, 8 waves = 4 qw x 2 kvh, grid 512, 64 KB LDS,
// in-register softmax). The restructure: QK(t+1) is hoisted BEFORE the
// buffer-release barrier, adjacent to PV(t) (independent: PV consumes pa(t)
// from the previous phase's SM; QK fills st for the next). Softmax runs at
// the phase tail, overlapping the stage-issue/wait window. Per-wave serial
// chain drops from QK+SM+PV to ~max(QK+PV)+SM-tail. Barrier count per tile
// unchanged (2); one stage (4 loads) in flight at every barrier; st stays
// single-buffered (no VGPR growth).
//   half-iter: vmcnt(0)[=S(t+1) only]; bar; {QK(t+1) || PV(t)} @prio1; bar;
//              stage(t+2); SM(t+1)->pa
// ---------------------------------------------------------------------------
__global__ __launch_bounds__(512, 4)
void flash_attn(const ushort* __restrict__ qb, const ushort* __restrict__ kb,
                const ushort* __restrict__ vtb, ushort* __restrict__ aob) {
    const int id = blockIdx.x;
    const int xcd = id & 7, slot = id >> 3;           // slot in [0,64)
    const int bh = xcd + 8 * (slot >> 4);             // 4 heads per XCD
    const int qt = slot & 15;
    const int tid = threadIdx.x, wave = tid >> 6, lane = tid & 63;
    const int l31 = lane & 31, l5 = lane >> 5;
    const int swz = l31 & 7;                          // row&7 swizzle key
    const int kvh = wave >> 2;                        // kv half for this wave
    const int qw = wave & 3;

    __shared__ __align__(16) ushort sm[32768];        // 64 KB
    ushort* Ksp = sm;                                 // [kvh][buf][4096]
    ushort* Vsp = sm + 16384;                         // [kvh][buf][4096]

    const ushort* Qb = qb + (size_t)bh * SEQ * DHEAD;
    const ushort* Kb = kb + (size_t)bh * SEQ * DHEAD;        // block-uniform
    const ushort* Vt = vtb + (size_t)bh * DHEAD * SEQ;       // block-uniform

    const int q0 = qt * 128 + qw * 32;

    // Q as B-operand of 32x32x16: lane holds Q[q0 + (lane&31)][kw*16 + l5*8 + e]
    short8 qf[4];
#pragma unroll
    for (int kw = 0; kw < 4; ++kw)
        qf[kw] = *(const short8*)(Qb + (size_t)(q0 + l31) * DHEAD + kw * 16 + l5 * 8);

    const int kofs = tid * 8;                  // 512 thr x 16B = one full 8KB tile
    const size_t vrow = (size_t)(tid >> 3) * SEQ;   // V d-row, [0,64)
    const int vcol = (tid & 7) * 8;

    const ushort* KsW = Ksp + kvh * 8192;
    const ushort* VsW = Vsp + kvh * 8192;

    floatx16 acc_o[2] = {};
    floatx16 st[2];                            // QK result, single-buffered
    uintx4 pa[4];                              // packed P fragments (from SM)
    float l_lane = 0.0f;

    // Exact staging: one async16 per 8KB tile (K half0, K half1, V half0, V half1)
#define S_STAGE(BUF, KV)                                                            \
    {                                                                               \
        const int kv_ = (KV);                                                       \
        async16(Kb + (size_t)kv_ * DHEAD + kofs,          (void*)(Ksp + (BUF) * 4096 + kofs));        \
        async16(Kb + (size_t)(1024 + kv_) * DHEAD + kofs, (void*)(Ksp + 8192 + (BUF) * 4096 + kofs)); \
        async16(Vt + vrow + kv_ + vcol,                   (void*)(Vsp + (BUF) * 4096 + kofs));        \
        async16(Vt + vrow + 1024 + kv_ + vcol,            (void*)(Vsp + 8192 + (BUF) * 4096 + kofs)); \
    }

    // P layout after mfma(K,Q): st[i][reg] = P[kv][q=l31],
    // kv = i*32 + (reg&3) + 4*l5 + 8*(reg>>2)  => kv bits:
    // kv0=reg0 kv1=reg1 kv2=l5 kv3=reg2 kv4=reg3 kv5=i.
    // PV A-fragment needs: lane5'=kv3, fragment kk=(kv5,kv4), elem e=kv[2:0].
    // cvt_pk packs kv0; permlane32_swap(a=reg2:0, b=reg2:1) exchanges
    // a.high<->b.low so a' = slot(kv2=0,kv1), b' = slot(kv2=1,kv1).
#define QK_STEP(BUF)                                                                \
    {                                                                               \
        _Pragma("unroll")                                                           \
        for (int e = 0; e < 16; ++e) { st[0][e] = 0.0f; st[1][e] = 0.0f; }          \
        _Pragma("unroll")                                                           \
        for (int kw = 0; kw < 4; ++kw) {                                            \
            _Pragma("unroll")                                                       \
            for (int i = 0; i < 2; ++i) {                                           \
                short8 kf = *(const short8*)(KsW + (BUF) * 4096 + (i * 32 + l31) * 64 + \
                                             (((kw * 2 + l5) ^ swz) * 8));          \
                st[i] = __builtin_amdgcn_mfma_f32_32x32x16_bf16(kf, qf[kw], st[i], 0, 0, 0); \
            }                                                                       \
        }                                                                           \
    }

#define SM_STEP()                                                                   \
    {                                                                               \
        _Pragma("unroll")                                                           \
        for (int i = 0; i < 2; ++i) {                                               \
            uint P2[8];                                                             \
            float lsA = 0.0f, lsB = 0.0f;                                           \
            _Pragma("unroll")                                                       \
            for (int rr = 0; rr < 8; ++rr) {                                        \
                const float p0 = fast_exp2(st[i][rr * 2]);                          \
                const float p1 = fast_exp2(st[i][rr * 2 + 1]);                      \
                if (rr & 1) lsB += p0 + p1; else lsA += p0 + p1;                    \
                P2[rr] = pack_bf16x2(p0, p1);                                       \
            }                                                                       \
            l_lane += lsA + lsB;                                                    \
            _Pragma("unroll")                                                       \
            for (int r3 = 0; r3 < 2; ++r3) {                                        \
                _Pragma("unroll")                                                   \
                for (int r1 = 0; r1 < 2; ++r1) {                                    \
                    uint a = P2[r3 * 4 + r1];        /* kv3=0 */                    \
                    uint b = P2[r3 * 4 + 2 + r1];    /* kv3=1 */                    \
                    asm volatile("v_permlane32_swap_b32 %0, %1" : "+v"(a), "+v"(b)); \
                    pa[i * 2 + r3][r1] = a;          /* slot (kv2=0, kv1=r1) */     \
                    pa[i * 2 + r3][2 + r1] = b;      /* slot (kv2=1, kv1=r1) */     \
                }                                                                   \
            }                                                                       \
        }                                                                           \
    }

#define PV_STEP(BUF)                                                                \
    {                                                                               \
        _Pragma("unroll")                                                           \
        for (int kk = 0; kk < 4; ++kk) {                                            \
            const short8 paf = *(const short8*)&pa[kk];                             \
            _Pragma("unroll")                                                       \
            for (int j2 = 0; j2 < 2; ++j2) {                                        \
                short8 vf = *(const short8*)(VsW + (BUF) * 4096 + (j2 * 32 + l31) * 64 + \
                                             (((kk * 2 + l5) ^ swz) * 8));          \
                acc_o[j2] = __builtin_amdgcn_mfma_f32_32x32x16_bf16(paf, vf, acc_o[j2], 0, 0, 0); \
            }                                                                       \
        }                                                                           \
    }

    // prologue: tiles 0,1 staged; QK(0)+SM(0) while S(1) flies
    S_STAGE(0, 0)
    S_STAGE(1, 64)
    WAITV4();                       // S(0) complete, S(1) in flight
    BAR_RAW();                      // publish buf0
    QK_STEP(0)
    SM_STEP()                       // pa = tile 0

    // 7 double-iterations handle tiles 0..13 (PV) / 1..14 (QK) / stage 2..15
    for (int kt = 0; kt < 14 * 64; kt += 128) {
        // half A: PV tile t (buf0), QK tile t+1 (buf1), stage t+2 -> buf0
        WAITV0();                   // only S(t+1) outstanding -> counted-equiv
        BAR_RAW();                  // publish buf1
        __builtin_amdgcn_s_setprio(1);
        QK_STEP(1)
        PV_STEP(0)
        __builtin_amdgcn_s_setprio(0);
        BAR_RAW();                  // all waves done reading buf0 (K last half, V now)
        S_STAGE(0, kt + 128)
        SM_STEP()                   // pa = tile t+1 (overlaps stage latency)
        // half B: PV tile t+1 (buf1), QK tile t+2 (buf0), stage t+3 -> buf1
        WAITV0();                   // only S(t+2) outstanding
        BAR_RAW();                  // publish buf0
        __builtin_amdgcn_s_setprio(1);
        QK_STEP(0)
        PV_STEP(1)
        __builtin_amdgcn_s_setprio(0);
        BAR_RAW();                  // all waves done reading buf1
        S_STAGE(1, kt + 192)
        SM_STEP()                   // pa = tile t+2
    }
    // tail: tiles 14 (pa ready) and 15
    WAITV0();                       // S(15) complete
    BAR_RAW();                      // publish buf1
    __builtin_amdgcn_s_setprio(1);
    QK_STEP(1)                      // tile 15 K from buf1
    PV_STEP(0)                      // tile 14 V from buf0
    __builtin_amdgcn_s_setprio(0);
    SM_STEP()                       // pa = tile 15
    __builtin_amdgcn_s_setprio(1);
    PV_STEP(1)                      // tile 15 V from buf1
    __builtin_amdgcn_s_setprio(0);
#undef S_STAGE
#undef QK_STEP
#undef SM_STEP
#undef PV_STEP

    // ---- KV-half merge: waves 4-7 hand their partial (O, l) to waves 0-3
    // (same qw). Lane mappings identical -> lane-wise add. Reuses sm:
    // 4 regions x 64 lanes x 36 floats = 36864 B (no outstanding DMA here).
    __syncthreads();
    float* mrg = (float*)sm;
    float* p = mrg + (size_t)(qw * 64 + lane) * 36;
    if (kvh == 1) {
#pragma unroll
        for (int j2 = 0; j2 < 2; ++j2)
#pragma unroll
            for (int r4 = 0; r4 < 4; ++r4) {
                floatx4 v;
                v[0] = acc_o[j2][r4 * 4 + 0];
                v[1] = acc_o[j2][r4 * 4 + 1];
                v[2] = acc_o[j2][r4 * 4 + 2];
                v[3] = acc_o[j2][r4 * 4 + 3];
                *(floatx4*)(p + j2 * 16 + r4 * 4) = v;
            }
        p[32] = l_lane;
    }
    __syncthreads();
    if (kvh == 0) {
#pragma unroll
        for (int j2 = 0; j2 < 2; ++j2)
#pragma unroll
            for (int r4 = 0; r4 < 4; ++r4) {
                floatx4 v = *(const floatx4*)(p + j2 * 16 + r4 * 4);
#pragma unroll
                for (int e = 0; e < 4; ++e)
                    acc_o[j2][r4 * 4 + e] += v[e];
            }
        l_lane += p[32];

        // each lane holds the partial rowsum for q = lane&31 over half the kv's
        l_lane += __shfl_xor(l_lane, 32);
        const float invl = 1.0f / l_lane;    // full rowsum for q = lane&31

        // epilogue: O rows q = (r&3)+4*l5+8*(r>>2), cols d = j2*32 + l31.
        // aob[srow][h*64 + d], chunk-swizzled (32-window, key (srow>>1)&3)
        const int b = bh >> 4, h = bh & 15;
#pragma unroll
        for (int r = 0; r < 16; ++r) {
            const int qrow = (r & 3) + 4 * l5 + 8 * (r >> 2);
            const float il = __shfl(invl, qrow);
            const int srow = b * SEQ + q0 + qrow;
            const int key = (srow >> 1) & 3;
#pragma unroll
            for (int j2 = 0; j2 < 2; ++j2) {
                const int d = j2 * 32 + l31;
                const int dsw = (d & ~31) | ((((d >> 3) & 3) ^ key) << 3) | (d & 7);
                aob[(size_t)srow * (NHEAD * DHEAD) + h * DHEAD + dsw] = f2bf(acc_o[j2][r] * il);
            }
        }
    }
}

// ---------------------------------------------------------------------------
extern "C" void kernel_launch(void* const* d_in, const int* in_sizes, int n_in,
                              void* d_out, int out_size, void* d_ws, size_t ws_size,
                              hipStream_t stream) {
    const float* x      = (const float*)d_in[0];   // [2,2048,1024]
    const float* w_qkv  = (const float*)d_in[1];   // [3072,1024]
    const float* w_proj = (const float*)d_in[2];   // [1024,1024]
    const float* b_proj = (const float*)d_in[3];   // [1024]
    float* out = (float*)d_out;                    // [2,2048,1024] fp32

    // workspace carve (all bf16/ushort): 24M elements = 48 MB
    ushort* ws = (ushort*)d_ws;
    ushort* xb     = ws;                                   // 4M
    ushort* wqkvb  = xb + (size_t)MROWS * NFEAT;           // 3M
    ushort* wprojb = wqkvb + (size_t)NQKV * NFEAT;         // 1M
    ushort* qb     = wprojb + (size_t)NFEAT * NFEAT;       // 4M
    ushort* kb     = qb + (size_t)MROWS * NFEAT;           // 4M
    ushort* vtb    = kb + (size_t)MROWS * NFEAT;           // 4M
    ushort* aob    = vtb + (size_t)MROWS * NFEAT;          // 4M

    // merged converts (swizzled outputs)
    {
        const int total = (MROWS * NFEAT + NQKV * NFEAT + NFEAT * NFEAT) / 4;
        cvt_swz<<<(total + 255) / 256, 256, 0, stream>>>(x, w_qkv, w_proj, xb, wqkvb, wprojb);
    }

    // QKV projection -> q (prescaled) / k (d-swizzled) / vt (s-swizzled)
    // 1D grid 768 with in-kernel XCD-locality decode
    {
        gemm_qkv<<<768, 256, 0, stream>>>(xb, wqkvb, qb, kb, vtb);
    }

    // flash attention -> aob [4096,1024] bf16 (swizzled); 512-thread blocks
    // (4 q-waves x 2 kv-halves), software-pipelined phases, grid 512
    {
        flash_attn<<<512, 512, 0, stream>>>(qb, kb, vtb, aob);
    }

    // output projection: out[4096,1024] = aob @ w_proj^T + b_proj (fp32)
    // 128x64 tiles, 256 threads, grid 512 with XCD decode (round-2 form)
    {
        gemm_proj<<<512, 256, 0, stream>>>(aob, wprojb, b_proj, out);
    }
}

// Round 9
// 176.167 us; speedup vs baseline: 1.2596x; 1.2596x over previous
//
#include <hip/hip_runtime.h>
#include <hip/hip_bf16.h>
#include <math.h>

// Problem constants
#define BATCH 2
#define SEQ 2048
#define NFEAT 1024
#define NHEAD 16
#define DHEAD 64
#define MROWS (BATCH * SEQ)      // 4096
#define NQKV (3 * NHEAD * DHEAD) // 3072

typedef __attribute__((ext_vector_type(8))) short short8;
typedef __attribute__((ext_vector_type(4))) float floatx4;
typedef __attribute__((ext_vector_type(16))) float floatx16;
typedef __attribute__((ext_vector_type(4))) unsigned int uintx4;

#define CEXP 0.18033688f   // log2(e)/sqrt(64), applied in gemm_qkv Q epilogue

__device__ __forceinline__ unsigned short f2bf(float f) {
    unsigned int u = __float_as_uint(f);
    u += 0x7fff + ((u >> 16) & 1);   // round-to-nearest-even
    return (unsigned short)(u >> 16);
}

__device__ __forceinline__ float fast_exp2(float x) {
    return __builtin_amdgcn_exp2f(x);   // v_exp_f32: D = 2^S0
}

__device__ __forceinline__ uint pack_bf16x2(float lo, float hi) {
    float2 t; t.x = lo; t.y = hi;
    __hip_bfloat162 h = __float22bfloat162_rn(t);   // v_cvt_pk_bf16_f32
    union { __hip_bfloat162 h; uint u; } c; c.h = h;
    return c.u;
}

__device__ __forceinline__ void async16(const void* g, void* l) {
    __builtin_amdgcn_global_load_lds(
        (const __attribute__((address_space(1))) void*)g,
        (__attribute__((address_space(3))) void*)l, 16, 0, 0);
}

// raw barrier + counted vmcnt (T4): loads stay in flight across barriers
#define BAR_RAW() asm volatile("s_barrier" ::: "memory")
#define WAITV4()  { asm volatile("s_waitcnt vmcnt(4)" ::: "memory"); __builtin_amdgcn_sched_barrier(0); }
#define WAITV0()  { asm volatile("s_waitcnt vmcnt(0)" ::: "memory"); __builtin_amdgcn_sched_barrier(0); }

// ---------------------------------------------------------------------------
// fp32 -> bf16 convert of x, w_qkv, w_proj, merged; output chunk-swizzled in
// 32-wide k-windows (key (row>>1)&3) so GEMM LDS fragment reads are 2-way max.
// ---------------------------------------------------------------------------
__global__ void cvt_swz(const float* __restrict__ x, const float* __restrict__ wq,
                        const float* __restrict__ wp,
                        ushort* __restrict__ xb, ushort* __restrict__ wqb,
                        ushort* __restrict__ wpb) {
    const int NX = MROWS * NFEAT / 4, NWQ = NQKV * NFEAT / 4, NWP = NFEAT * NFEAT / 4;
    int i = blockIdx.x * blockDim.x + threadIdx.x;
    if (i >= NX + NWQ + NWP) return;
    const float* src; ushort* dst; int idx4;
    if (i < NX)            { src = x;  dst = xb;  idx4 = i; }
    else if (i < NX + NWQ) { src = wq; dst = wqb; idx4 = i - NX; }
    else                   { src = wp; dst = wpb; idx4 = i - NX - NWQ; }
    float4 v = ((const float4*)src)[idx4];
    ushort4 o;
    o.x = f2bf(v.x); o.y = f2bf(v.y); o.z = f2bf(v.z); o.w = f2bf(v.w);
    const int e = idx4 * 4;
    const int k = e & (NFEAT - 1);
    const int row = e >> 10;                     // all arrays have K = 1024
    const int kp = (k & ~31) | (((((k >> 3) & 3) ^ ((row >> 1) & 3))) << 3) | (k & 7);
    *(ushort4*)(dst + (size_t)row * NFEAT + kp) = o;
}

// ---------------------------------------------------------------------------
// QKV GEMM: 128x128 tile, BK=64 (16 barriers x 32 MFMAs). 1D grid 768 with
// XCD-locality decode: 8 regions of 8 m-tiles x 12 n-tiles, region = id%8,
// so blocks sharing A-rows/W-cols co-reside on one XCD's L2.
// Epilogue is the round-12 measured-good form (scalar Q/K + V^T transpose).
// NOTE (rounds 10/11): swapped-operand epilogues caused ~8x HBM write
// amplification (166/198 MB vs 24 MB ideal). Watch WRITE_SIZE on any change.
// ---------------------------------------------------------------------------
__global__ __launch_bounds__(256, 3)
void gemm_qkv(const ushort* __restrict__ A, const ushort* __restrict__ W,
              ushort* __restrict__ qb, ushort* __restrict__ kb, ushort* __restrict__ vtb) {
    __shared__ ushort smem[16384];      // As: [0,8192) Bs: [8192,16384); epilogue reuses front
    ushort* As = smem;
    ushort* Bs = smem + 8192;
    const int tid = threadIdx.x;
    const int wave = tid >> 6, lane = tid & 63;
    // XCD-locality decode: region (id&7) = 8 by x 12 bx; slot = id>>3 in [0,96)
    const int id = blockIdx.x;
    const int xcd = id & 7, slot = id >> 3;
    const int by = (xcd >> 1) * 8 + slot / 12;
    const int bx = (xcd & 1) * 12 + slot % 12;
    const int m0 = by * 128, n0 = bx * 128;
    const int wm = (wave >> 1) * 64, wn = (wave & 1) * 64;
    const int lr = lane & 15, lg = lane >> 4;
    const int kswz = (lg ^ ((lr >> 1) & 3)) * 8;   // de-swizzle slot within 32-window

    floatx4 acc[4][4] = {};

    for (int k0 = 0; k0 < NFEAT; k0 += 64) {
#pragma unroll
        for (int q = 0; q < 4; ++q) {
            const int s = q * 256 + tid;
            const int row = s >> 3, kc = (s & 7) * 8;
            async16(A + (size_t)(m0 + row) * NFEAT + k0 + kc, (void*)(As + s * 8));
            async16(W + (size_t)(n0 + row) * NFEAT + k0 + kc, (void*)(Bs + s * 8));
        }
        __syncthreads();
#pragma unroll
        for (int kk = 0; kk < 2; ++kk) {
            short8 a[4], b[4];
#pragma unroll
            for (int i = 0; i < 4; ++i)
                a[i] = *(const short8*)(As + (wm + i * 16 + lr) * 64 + kk * 32 + kswz);
#pragma unroll
            for (int j = 0; j < 4; ++j)
                b[j] = *(const short8*)(Bs + (wn + j * 16 + lr) * 64 + kk * 32 + kswz);
#pragma unroll
            for (int i = 0; i < 4; ++i)
#pragma unroll
                for (int j = 0; j < 4; ++j)
                    acc[i][j] = __builtin_amdgcn_mfma_f32_16x16x32_bf16(a[i], b[j], acc[i][j], 0, 0, 0);
        }
        __syncthreads();
    }

    const int t = n0 >> 10;         // block-uniform
    const int bidx = m0 >> 11;
    if (t < 2) {
#pragma unroll
        for (int i = 0; i < 4; ++i)
#pragma unroll
            for (int j = 0; j < 4; ++j)
#pragma unroll
                for (int r = 0; r < 4; ++r) {
                    const int m = m0 + wm + i * 16 + lg * 4 + r;
                    const int n = n0 + wn + j * 16 + lr;
                    const int s = m & (SEQ - 1);
                    const int rem = n & 1023, h = rem >> 6, d = rem & 63;
                    if (t == 0) {
                        qb[((size_t)(bidx * NHEAD + h) * SEQ + s) * DHEAD + d] =
                            f2bf(acc[i][j][r] * CEXP);
                    } else {
                        const int dcol = ((((d >> 3) ^ (s & 7)) << 3)) | (d & 7);
                        kb[((size_t)(bidx * NHEAD + h) * SEQ + s) * DHEAD + dcol] =
                            f2bf(acc[i][j][r]);
                    }
                }
    } else {
        // V^T: LDS transpose, two 64-row m-halves, coalesced 16B stores.
#pragma unroll
        for (int hhalf = 0; hhalf < 2; ++hhalf) {
            if ((wm >> 6) == hhalf) {
#pragma unroll
                for (int i = 0; i < 4; ++i) {
                    const int chunk = i * 2 + (lg >> 1);
#pragma unroll
                    for (int j = 0; j < 4; ++j) {
                        const int n = wn + j * 16 + lr;
                        uint2 pk;
                        pk.x = pack_bf16x2(acc[i][j][0], acc[i][j][1]);
                        pk.y = pack_bf16x2(acc[i][j][2], acc[i][j][3]);
                        *(uint2*)(smem + n * 64 + ((chunk ^ (n & 7)) * 8) + (lg & 1) * 4) = pk;
                    }
                }
            }
            __syncthreads();
            // s index is WITHIN-BATCH: (m0 & (SEQ-1)), not m0.
            const int s_base = (m0 & (SEQ - 1)) + hhalf * 64;
#pragma unroll
            for (int it = 0; it < 4; ++it) {
                const int n_r = (tid >> 3) + it * 32;
                const int p = tid & 7;
                short8 rowv = *(const short8*)(smem + n_r * 64 + p * 8);
                const int nglob = n0 + n_r;
                const int d = nglob & 63, hh = (nglob & 1023) >> 6;
                *(short8*)(vtb + ((size_t)(bidx * NHEAD + hh) * DHEAD + d) * SEQ + s_base + p * 8) = rowv;
            }
            __syncthreads();
        }
    }
}

// ---------------------------------------------------------------------------
// Output projection GEMM (round-2 measured-good form): 128m x 64n, BK=64.
// 1D grid 512 with XCD decode: 8 regions of 8 by x 8 bx, 2 blocks/CU.
// out = A @ w_proj^T + bias, fp32.
// ---------------------------------------------------------------------------
__global__ __launch_bounds__(256, 2)
void gemm_proj(const ushort* __restrict__ A, const ushort* __restrict__ W,
               const float* __restrict__ bias, float* __restrict__ Cout) {
    __shared__ ushort As[128 * 64];   // 16 KB
    __shared__ ushort Bs[64 * 64];    // 8 KB
    const int tid = threadIdx.x;
    const int wave = tid >> 6, lane = tid & 63;
    const int id = blockIdx.x;
    const int xcd = id & 7, slot = id >> 3;           // slot in [0,64)
    const int by = (xcd >> 1) * 8 + (slot >> 3);
    const int bx = (xcd & 1) * 8 + (slot & 7);
    const int m0 = by * 128, n0 = bx * 64;
    const int wm = (wave >> 1) * 64, wn = (wave & 1) * 32;
    const int lr = lane & 15, lg = lane >> 4;
    const int kswz = (lg ^ ((lr >> 1) & 3)) * 8;

    floatx4 acc[4][2] = {};

    for (int k0 = 0; k0 < NFEAT; k0 += 64) {
#pragma unroll
        for (int q = 0; q < 4; ++q) {
            const int s = q * 256 + tid;
            const int row = s >> 3, kc = (s & 7) * 8;
            async16(A + (size_t)(m0 + row) * NFEAT + k0 + kc, (void*)(As + s * 8));
        }
#pragma unroll
        for (int q = 0; q < 2; ++q) {
            const int s = q * 256 + tid;
            const int row = s >> 3, kc = (s & 7) * 8;
            async16(W + (size_t)(n0 + row) * NFEAT + k0 + kc, (void*)(Bs + s * 8));
        }
        __syncthreads();
#pragma unroll
        for (int kk = 0; kk < 2; ++kk) {
            short8 a[4], b[2];
#pragma unroll
            for (int i = 0; i < 4; ++i)
                a[i] = *(const short8*)(As + (wm + i * 16 + lr) * 64 + kk * 32 + kswz);
#pragma unroll
            for (int j = 0; j < 2; ++j)
                b[j] = *(const short8*)(Bs + (wn + j * 16 + lr) * 64 + kk * 32 + kswz);
#pragma unroll
            for (int i = 0; i < 4; ++i)
#pragma unroll
                for (int j = 0; j < 2; ++j)
                    acc[i][j] = __builtin_amdgcn_mfma_f32_16x16x32_bf16(a[i], b[j], acc[i][j], 0, 0, 0);
        }
        __syncthreads();
    }

#pragma unroll
    for (int i = 0; i < 4; ++i)
#pragma unroll
        for (int j = 0; j < 2; ++j)
#pragma unroll
            for (int r = 0; r < 4; ++r) {
                const int m = m0 + wm + i * 16 + lg * 4 + r;
                const int n = n0 + wn + j * 16 + lr;
                Cout[(size_t)m * NFEAT + n] = acc[i][j][r] + bias[n];
            }
}

// ---------------------------------------------------------------------------
// Flash attention v13b: round-7's software-pipelined schedule with the
// register budget FIXED. Round 7 regressed purely from scratch spill:
// __launch_bounds__(512,4) let the allocator target 8 waves/EU (64-VGPR),
// spilling ~6 regs/tile (FETCH 125MB / WRITE 98MB of scratch). The grid is
// 512 = 2 blocks/CU regardless, so dropping the waves hint changes NOTHING
// about real occupancy (16 waves/CU) -- it only lets the allocator keep
// st[2]+pa[4] in registers (~110-120 VGPR, cap 128 at 4 waves/EU).
// Schedule per half-iter: vmcnt(0)[=next stage only]; bar;
//   {QK(t+1) || PV(t)} @prio1; bar; stage(t+2); SM(t+1)->pa.
// ---------------------------------------------------------------------------
__global__ __launch_bounds__(512)
void flash_attn(const ushort* __restrict__ qb, const ushort* __restrict__ kb,
                const ushort* __restrict__ vtb, ushort* __restrict__ aob) {
    const int id = blockIdx.x;
    const int xcd = id & 7, slot = id >> 3;           // slot in [0,64)
    const int bh = xcd + 8 * (slot >> 4);             // 4 heads per XCD
    const int qt = slot & 15;
    const int tid = threadIdx.x, wave = tid >> 6, lane = tid & 63;
    const int l31 = lane & 31, l5 = lane >> 5;
    const int swz = l31 & 7;                          // row&7 swizzle key
    const int kvh = wave >> 2;                        // kv half for this wave
    const int qw = wave & 3;

    __shared__ __align__(16) ushort sm[32768];        // 64 KB
    ushort* Ksp = sm;                                 // [kvh][buf][4096]
    ushort* Vsp = sm + 16384;                         // [kvh][buf][4096]

    const ushort* Qb = qb + (size_t)bh * SEQ * DHEAD;
    const ushort* Kb = kb + (size_t)bh * SEQ * DHEAD;        // block-uniform
    const ushort* Vt = vtb + (size_t)bh * DHEAD * SEQ;       // block-uniform

    const int q0 = qt * 128 + qw * 32;

    // Q as B-operand of 32x32x16: lane holds Q[q0 + (lane&31)][kw*16 + l5*8 + e]
    short8 qf[4];
#pragma unroll
    for (int kw = 0; kw < 4; ++kw)
        qf[kw] = *(const short8*)(Qb + (size_t)(q0 + l31) * DHEAD + kw * 16 + l5 * 8);

    const int kofs = tid * 8;                  // 512 thr x 16B = one full 8KB tile
    const size_t vrow = (size_t)(tid >> 3) * SEQ;   // V d-row, [0,64)
    const int vcol = (tid & 7) * 8;

    const ushort* KsW = Ksp + kvh * 8192;
    const ushort* VsW = Vsp + kvh * 8192;

    floatx16 acc_o[2] = {};
    floatx16 st[2];                            // QK result, single-buffered
    uintx4 pa[4];                              // packed P fragments (from SM)
    float l_lane = 0.0f;

    // Exact staging: one async16 per 8KB tile (K half0, K half1, V half0, V half1)
#define S_STAGE(BUF, KV)                                                            \
    {                                                                               \
        const int kv_ = (KV);                                                       \
        async16(Kb + (size_t)kv_ * DHEAD + kofs,          (void*)(Ksp + (BUF) * 4096 + kofs));        \
        async16(Kb + (size_t)(1024 + kv_) * DHEAD + kofs, (void*)(Ksp + 8192 + (BUF) * 4096 + kofs)); \
        async16(Vt + vrow + kv_ + vcol,                   (void*)(Vsp + (BUF) * 4096 + kofs));        \
        async16(Vt + vrow + 1024 + kv_ + vcol,            (void*)(Vsp + 8192 + (BUF) * 4096 + kofs)); \
    }

    // P layout after mfma(K,Q): st[i][reg] = P[kv][q=l31],
    // kv = i*32 + (reg&3) + 4*l5 + 8*(reg>>2)  => kv bits:
    // kv0=reg0 kv1=reg1 kv2=l5 kv3=reg2 kv4=reg3 kv5=i.
    // PV A-fragment needs: lane5'=kv3, fragment kk=(kv5,kv4), elem e=kv[2:0].
    // cvt_pk packs kv0; permlane32_swap(a=reg2:0, b=reg2:1) exchanges
    // a.high<->b.low so a' = slot(kv2=0,kv1), b' = slot(kv2=1,kv1).
#define QK_STEP(BUF)                                                                \
    {                                                                               \
        _Pragma("unroll")                                                           \
        for (int e = 0; e < 16; ++e) { st[0][e] = 0.0f; st[1][e] = 0.0f; }          \
        _Pragma("unroll")                                                           \
        for (int kw = 0; kw < 4; ++kw) {                                            \
            _Pragma("unroll")                                                       \
            for (int i = 0; i < 2; ++i) {                                           \
                short8 kf = *(const short8*)(KsW + (BUF) * 4096 + (i * 32 + l31) * 64 + \
                                             (((kw * 2 + l5) ^ swz) * 8));          \
                st[i] = __builtin_amdgcn_mfma_f32_32x32x16_bf16(kf, qf[kw], st[i], 0, 0, 0); \
            }                                                                       \
        }                                                                           \
    }

#define SM_STEP()                                                                   \
    {                                                                               \
        _Pragma("unroll")                                                           \
        for (int i = 0; i < 2; ++i) {                                               \
            uint P2[8];                                                             \
            float lsA = 0.0f, lsB = 0.0f;                                           \
            _Pragma("unroll")                                                       \
            for (int rr = 0; rr < 8; ++rr) {                                        \
                const float p0 = fast_exp2(st[i][rr * 2]);                          \
                const float p1 = fast_exp2(st[i][rr * 2 + 1]);                      \
                if (rr & 1) lsB += p0 + p1; else lsA += p0 + p1;                    \
                P2[rr] = pack_bf16x2(p0, p1);                                       \
            }                                                                       \
            l_lane += lsA + lsB;                                                    \
            _Pragma("unroll")                                                       \
            for (int r3 = 0; r3 < 2; ++r3) {                                        \
                _Pragma("unroll")                                                   \
                for (int r1 = 0; r1 < 2; ++r1) {                                    \
                    uint a = P2[r3 * 4 + r1];        /* kv3=0 */                    \
                    uint b = P2[r3 * 4 + 2 + r1];    /* kv3=1 */                    \
                    asm volatile("v_permlane32_swap_b32 %0, %1" : "+v"(a), "+v"(b)); \
                    pa[i * 2 + r3][r1] = a;          /* slot (kv2=0, kv1=r1) */     \
                    pa[i * 2 + r3][2 + r1] = b;      /* slot (kv2=1, kv1=r1) */     \
                }                                                                   \
            }                                                                       \
        }                                                                           \
    }

#define PV_STEP(BUF)                                                                \
    {                                                                               \
        _Pragma("unroll")                                                           \
        for (int kk = 0; kk < 4; ++kk) {                                            \
            const short8 paf = *(const short8*)&pa[kk];                             \
            _Pragma("unroll")                                                       \
            for (int j2 = 0; j2 < 2; ++j2) {                                        \
                short8 vf = *(const short8*)(VsW + (BUF) * 4096 + (j2 * 32 + l31) * 64 + \
                                             (((kk * 2 + l5) ^ swz) * 8));          \
                acc_o[j2] = __builtin_amdgcn_mfma_f32_32x32x16_bf16(paf, vf, acc_o[j2], 0, 0, 0); \
            }                                                                       \
        }                                                                           \
    }

    // prologue: tiles 0,1 staged; QK(0)+SM(0) while S(1) flies
    S_STAGE(0, 0)
    S_STAGE(1, 64)
    WAITV4();                       // S(0) complete, S(1) in flight
    BAR_RAW();                      // publish buf0
    QK_STEP(0)
    SM_STEP()                       // pa = tile 0

    // 7 double-iterations handle tiles 0..13 (PV) / 1..14 (QK) / stage 2..15
    for (int kt = 0; kt < 14 * 64; kt += 128) {
        // half A: PV tile t (buf0), QK tile t+1 (buf1), stage t+2 -> buf0
        WAITV0();                   // only S(t+1) outstanding -> counted-equiv
        BAR_RAW();                  // publish buf1
        __builtin_amdgcn_s_setprio(1);
        QK_STEP(1)
        PV_STEP(0)
        __builtin_amdgcn_s_setprio(0);
        BAR_RAW();                  // all waves done reading buf0 (K last half, V now)
        S_STAGE(0, kt + 128)
        SM_STEP()                   // pa = tile t+1 (overlaps stage latency)
        // half B: PV tile t+1 (buf1), QK tile t+2 (buf0), stage t+3 -> buf1
        WAITV0();                   // only S(t+2) outstanding
        BAR_RAW();                  // publish buf0
        __builtin_amdgcn_s_setprio(1);
        QK_STEP(0)
        PV_STEP(1)
        __builtin_amdgcn_s_setprio(0);
        BAR_RAW();                  // all waves done reading buf1
        S_STAGE(1, kt + 192)
        SM_STEP()                   // pa = tile t+2
    }
    // tail: tiles 14 (pa ready) and 15
    WAITV0();                       // S(15) complete
    BAR_RAW();                      // publish buf1
    __builtin_amdgcn_s_setprio(1);
    QK_STEP(1)                      // tile 15 K from buf1
    PV_STEP(0)                      // tile 14 V from buf0
    __builtin_amdgcn_s_setprio(0);
    SM_STEP()                       // pa = tile 15
    __builtin_amdgcn_s_setprio(1);
    PV_STEP(1)                      // tile 15 V from buf1
    __builtin_amdgcn_s_setprio(0);
#undef S_STAGE
#undef QK_STEP
#undef SM_STEP
#undef PV_STEP

    // ---- KV-half merge: waves 4-7 hand their partial (O, l) to waves 0-3
    // (same qw). Lane mappings identical -> lane-wise add. Reuses sm:
    // 4 regions x 64 lanes x 36 floats = 36864 B (no outstanding DMA here).
    __syncthreads();
    float* mrg = (float*)sm;
    float* p = mrg + (size_t)(qw * 64 + lane) * 36;
    if (kvh == 1) {
#pragma unroll
        for (int j2 = 0; j2 < 2; ++j2)
#pragma unroll
            for (int r4 = 0; r4 < 4; ++r4) {
                floatx4 v;
                v[0] = acc_o[j2][r4 * 4 + 0];
                v[1] = acc_o[j2][r4 * 4 + 1];
                v[2] = acc_o[j2][r4 * 4 + 2];
                v[3] = acc_o[j2][r4 * 4 + 3];
                *(floatx4*)(p + j2 * 16 + r4 * 4) = v;
            }
        p[32] = l_lane;
    }
    __syncthreads();
    if (kvh == 0) {
#pragma unroll
        for (int j2 = 0; j2 < 2; ++j2)
#pragma unroll
            for (int r4 = 0; r4 < 4; ++r4) {
                floatx4 v = *(const floatx4*)(p + j2 * 16 + r4 * 4);
#pragma unroll
                for (int e = 0; e < 4; ++e)
                    acc_o[j2][r4 * 4 + e] += v[e];
            }
        l_lane += p[32];

        // each lane holds the partial rowsum for q = lane&31 over half the kv's
        l_lane += __shfl_xor(l_lane, 32);
        const float invl = 1.0f / l_lane;    // full rowsum for q = lane&31

        // epilogue: O rows q = (r&3)+4*l5+8*(r>>2), cols d = j2*32 + l31.
        // aob[srow][h*64 + d], chunk-swizzled (32-window, key (srow>>1)&3)
        const int b = bh >> 4, h = bh & 15;
#pragma unroll
        for (int r = 0; r < 16; ++r) {
            const int qrow = (r & 3) + 4 * l5 + 8 * (r >> 2);
            const float il = __shfl(invl, qrow);
            const int srow = b * SEQ + q0 + qrow;
            const int key = (srow >> 1) & 3;
#pragma unroll
            for (int j2 = 0; j2 < 2; ++j2) {
                const int d = j2 * 32 + l31;
                const int dsw = (d & ~31) | ((((d >> 3) & 3) ^ key) << 3) | (d & 7);
                aob[(size_t)srow * (NHEAD * DHEAD) + h * DHEAD + dsw] = f2bf(acc_o[j2][r] * il);
            }
        }
    }
}

// ---------------------------------------------------------------------------
extern "C" void kernel_launch(void* const* d_in, const int* in_sizes, int n_in,
                              void* d_out, int out_size, void* d_ws, size_t ws_size,
                              hipStream_t stream) {
    const float* x      = (const float*)d_in[0];   // [2,2048,1024]
    const float* w_qkv  = (const float*)d_in[1];   // [3072,1024]
    const float* w_proj = (const float*)d_in[2];   // [1024,1024]
    const float* b_proj = (const float*)d_in[3];   // [1024]
    float* out = (float*)d_out;                    // [2,2048,1024] fp32

    // workspace carve (all bf16/ushort): 24M elements = 48 MB
    ushort* ws = (ushort*)d_ws;
    ushort* xb     = ws;                                   // 4M
    ushort* wqkvb  = xb + (size_t)MROWS * NFEAT;           // 3M
    ushort* wprojb = wqkvb + (size_t)NQKV * NFEAT;         // 1M
    ushort* qb     = wprojb + (size_t)NFEAT * NFEAT;       // 4M
    ushort* kb     = qb + (size_t)MROWS * NFEAT;           // 4M
    ushort* vtb    = kb + (size_t)MROWS * NFEAT;           // 4M
    ushort* aob    = vtb + (size_t)MROWS * NFEAT;          // 4M

    // merged converts (swizzled outputs)
    {
        const int total = (MROWS * NFEAT + NQKV * NFEAT + NFEAT * NFEAT) / 4;
        cvt_swz<<<(total + 255) / 256, 256, 0, stream>>>(x, w_qkv, w_proj, xb, wqkvb, wprojb);
    }

    // QKV projection -> q (prescaled) / k (d-swizzled) / vt (s-swizzled)
    // 1D grid 768 with in-kernel XCD-locality decode
    {
        gemm_qkv<<<768, 256, 0, stream>>>(xb, wqkvb, qb, kb, vtb);
    }

    // flash attention -> aob [4096,1024] bf16 (swizzled); 512-thread blocks
    // (4 q-waves x 2 kv-halves), software-pipelined phases, grid 512
    {
        flash_attn<<<512, 512, 0, stream>>>(qb, kb, vtb, aob);
    }

    // output projection: out[4096,1024] = aob @ w_proj^T + b_proj (fp32)
    // 128x64 tiles, 256 threads, grid 512 with XCD decode (round-2 form)
    {
        gemm_proj<<<512, 256, 0, stream>>>(aob, wprojb, b_proj, out);
    }
}